// Round 12
// baseline (341.361 us; speedup 1.0000x reference)
//
#include <hip/hip_runtime.h>
#include <hip/hip_bf16.h>

// ---------------------------------------------------------------------------
// GraphSAGE 3-layer forward, transform-before-aggregate everywhere.
//   layer: h' = ReLU( mean_agg(h @ Wl^T) + h @ Wr^T + b )   (mean is linear)
// Per layer: dual GEMM (K=128) -> u = h@Wl^T (fp8), v = h@Wr^T + b (bf16);
// then fused gather: h' = ReLU(mean(u) + v).
// GEMMs: column-split 1-wave blocks -- W fragments fully register-resident
// (16 frags), all loads hoisted, no mid-kernel latency stalls.
// CSR: single-pass padded-bucket counting sort.
// Layer 3: same pattern, tail fuses mean+add+log_softmax.
// ---------------------------------------------------------------------------

#define N_FEAT 128
#define NBMAX 512          // max coarse buckets (node width 256)
#define BCAP  5120         // padded bucket capacity (mean ~4092, +16 sigma)
#define SCHUNK 8192        // edges per block in scatter pass (256 thr x 32)

typedef __attribute__((ext_vector_type(8))) short short8;   // 8 bf16 = 4 VGPRs
typedef __attribute__((ext_vector_type(4))) float f32x4;
typedef __attribute__((ext_vector_type(2))) float f32x2;

__device__ __forceinline__ ushort f2bf(float f) {
    union { float f; uint u; } v; v.f = f;
    uint u = v.u;
    return (ushort)((u + 0x7fffu + ((u >> 16) & 1u)) >> 16);   // RNE
}
__device__ __forceinline__ uint pack2bf(float x, float y) {
    return (uint)f2bf(x) | ((uint)f2bf(y) << 16);
}
__device__ __forceinline__ float bflo(uint v) {
    union { uint u; float f; } c; c.u = v << 16; return c.f;
}
__device__ __forceinline__ float bfhi(uint v) {
    union { uint u; float f; } c; c.u = v & 0xffff0000u; return c.f;
}
__device__ __forceinline__ void acc8(float* acc, uint4 v) {
    acc[0] += bflo(v.x); acc[1] += bfhi(v.x);
    acc[2] += bflo(v.y); acc[3] += bfhi(v.y);
    acc[4] += bflo(v.z); acc[5] += bfhi(v.z);
    acc[6] += bflo(v.w); acc[7] += bfhi(v.w);
}
// decode 16 fp8 (uint4) -> acc[16] (fp32 accumulate)
__device__ __forceinline__ void accf8(float* acc, uint4 v) {
    f32x2 p;
    p = __builtin_amdgcn_cvt_pk_f32_fp8((int)v.x, false); acc[0] += p.x;  acc[1] += p.y;
    p = __builtin_amdgcn_cvt_pk_f32_fp8((int)v.x, true);  acc[2] += p.x;  acc[3] += p.y;
    p = __builtin_amdgcn_cvt_pk_f32_fp8((int)v.y, false); acc[4] += p.x;  acc[5] += p.y;
    p = __builtin_amdgcn_cvt_pk_f32_fp8((int)v.y, true);  acc[6] += p.x;  acc[7] += p.y;
    p = __builtin_amdgcn_cvt_pk_f32_fp8((int)v.z, false); acc[8] += p.x;  acc[9] += p.y;
    p = __builtin_amdgcn_cvt_pk_f32_fp8((int)v.z, true);  acc[10] += p.x; acc[11] += p.y;
    p = __builtin_amdgcn_cvt_pk_f32_fp8((int)v.w, false); acc[12] += p.x; acc[13] += p.y;
    p = __builtin_amdgcn_cvt_pk_f32_fp8((int)v.w, true);  acc[14] += p.x; acc[15] += p.y;
}
__device__ __forceinline__ uint pack4fp8(float a, float b, float c, float d) {
    int u = __builtin_amdgcn_cvt_pk_fp8_f32(a, b, 0, false);
    u = __builtin_amdgcn_cvt_pk_fp8_f32(c, d, u, true);
    return (uint)u;
}

// ---------------- block inclusive scan helper (256 threads) ----------------
__device__ __forceinline__ int block_inclusive_scan256(int v, int* lds_waves, int tid) {
    int lane = tid & 63;
    int wid  = tid >> 6;
#pragma unroll
    for (int d = 1; d < 64; d <<= 1) {
        int t = __shfl_up(v, d, 64);
        if (lane >= d) v += t;
    }
    if (lane == 63) lds_waves[wid] = v;
    __syncthreads();
    if (wid == 0) {
        int s = (lane < 4) ? lds_waves[lane] : 0;
#pragma unroll
        for (int d = 1; d < 4; d <<= 1) {
            int t = __shfl_up(s, d, 64);
            if (lane >= d) s += t;
        }
        if (lane < 4) lds_waves[lane] = s;
    }
    __syncthreads();
    int add = (wid > 0) ? lds_waves[wid - 1] : 0;
    return v + add;
}

// ---------------- init per-bucket cursors ----------------
__global__ void csr_init_kernel(int* __restrict__ gcursor) {
    int b = blockIdx.x * 256 + threadIdx.x;
    if (b < NBMAX) gcursor[b] = b * BCAP;
}

// ---------------- scatter packed (dloc<<24|src) into padded buckets ---------
__global__ void bucket_scatter_kernel(const int* __restrict__ src, const int* __restrict__ dst,
                                      int* __restrict__ gcursor, uint* __restrict__ bucketArr,
                                      int E, int NB) {
    __shared__ int cnt[NBMAX];
    __shared__ int gbase[NBMAX];
    int tid = threadIdx.x;
    for (int i = tid; i < NB; i += 256) cnt[i] = 0;
    __syncthreads();
    int base = blockIdx.x * SCHUNK;
    int4 sv[8], dv[8];
    int r[32];
#pragma unroll
    for (int b = 0; b < 8; ++b) {
        int idx = base + b * 1024 + tid * 4;
        if (idx < E) {
            sv[b] = *(const int4*)&src[idx];
            dv[b] = *(const int4*)&dst[idx];
        }
    }
#pragma unroll
    for (int b = 0; b < 8; ++b) {
        int idx = base + b * 1024 + tid * 4;
        if (idx < E) {
            r[b * 4 + 0] = atomicAdd(&cnt[dv[b].x >> 8], 1);
            r[b * 4 + 1] = atomicAdd(&cnt[dv[b].y >> 8], 1);
            r[b * 4 + 2] = atomicAdd(&cnt[dv[b].z >> 8], 1);
            r[b * 4 + 3] = atomicAdd(&cnt[dv[b].w >> 8], 1);
        }
    }
    __syncthreads();
    for (int i = tid; i < NB; i += 256)
        if (cnt[i]) gbase[i] = atomicAdd(&gcursor[i], cnt[i]);
    __syncthreads();
#pragma unroll
    for (int b = 0; b < 8; ++b) {
        int idx = base + b * 1024 + tid * 4;
        if (idx < E) {
            int ss[4] = { sv[b].x, sv[b].y, sv[b].z, sv[b].w };
            int dd[4] = { dv[b].x, dv[b].y, dv[b].z, dv[b].w };
#pragma unroll
            for (int j = 0; j < 4; ++j) {
                int bk = dd[j] >> 8;
                int pos = gbase[bk] + r[b * 4 + j];
                if (pos < (bk + 1) * BCAP) {     // overflow drop-guard
                    bucketArr[pos] = ((uint)(dd[j] & 255) << 24) | (uint)ss[j];
                }
            }
        }
    }
}

// ---------------- per-bucket CSR build: offs/deg + csr (padded) -------------
__global__ void bucket_build_kernel(const uint* __restrict__ bucketArr,
                                    const int* __restrict__ gcursor,
                                    int* __restrict__ offs, int* __restrict__ deg,
                                    int* __restrict__ csr, int n) {
    __shared__ int cnt[256];
    __shared__ int lds[4];
    int b = blockIdx.x, tid = threadIdx.x;
    int ebase = b * BCAP;
    int eend = gcursor[b];
    if (eend > ebase + BCAP) eend = ebase + BCAP;
    cnt[tid] = 0;
    __syncthreads();
    for (int i = ebase + tid; i < eend; i += 256)
        atomicAdd(&cnt[bucketArr[i] >> 24], 1);
    __syncthreads();
    int v = cnt[tid];
    int incl = block_inclusive_scan256(v, lds, tid);
    int excl = incl - v;
    int node = b * 256 + tid;
    if (node < n) { offs[node] = ebase + excl; deg[node] = v; }
    __syncthreads();
    cnt[tid] = excl;
    __syncthreads();
    for (int i = ebase + tid; i < eend; i += 256) {
        uint p = bucketArr[i];
        int pos = ebase + atomicAdd(&cnt[p >> 24], 1);
        csr[pos] = (int)(p & 0xFFFFFFu);
    }
}

// ---------------- merged prep: x->bf16 + fragment-major weight repacks ------
// Stacked [Wl;Wr] (256 rows, K=128): Wf[(ct*4+ks)*64+lane]*8, ct 0..15.
__device__ __forceinline__ void wcat2F_body(int tid, const float* Wl, const float* Wr,
                                            ushort* out) {
    int lane = tid & 63, ks = (tid >> 6) & 3, ct = tid >> 8;   // ct 0..15
    int lr = lane & 15, kg = lane >> 4;
    int row = ct * 16 + lr, k = ks * 32 + kg * 8;
    const float* s = (row < 128) ? &Wl[(size_t)row * 128 + k]
                                 : &Wr[(size_t)(row - 128) * 128 + k];
    float4 v0 = *(const float4*)s;
    float4 v1 = *(const float4*)(s + 4);
    uint4 o;
    o.x = pack2bf(v0.x, v0.y); o.y = pack2bf(v0.z, v0.w);
    o.z = pack2bf(v1.x, v1.y); o.w = pack2bf(v1.z, v1.w);
    *(uint4*)&out[(size_t)tid * 8] = o;
}
// Stacked [W2l;W2r] (128 rows): Wf3[(ct*4+ks)*64+lane]*8, ct 0..7.
__device__ __forceinline__ void wcat3F_body(int tid, const float* W2l, const float* W2r,
                                            ushort* out) {
    int lane = tid & 63, ks = (tid >> 6) & 3, ct = tid >> 8;
    int lr = lane & 15, kg = lane >> 4;
    int row = ct * 16 + lr, k = ks * 32 + kg * 8;
    const float* s = (row < 64) ? &W2l[(size_t)row * 128 + k] : &W2r[(size_t)(row - 64) * 128 + k];
    float4 v0 = *(const float4*)s;
    float4 v1 = *(const float4*)(s + 4);
    uint4 o;
    o.x = pack2bf(v0.x, v0.y); o.y = pack2bf(v0.z, v0.w);
    o.z = pack2bf(v1.x, v1.y); o.w = pack2bf(v1.z, v1.w);
    *(uint4*)&out[(size_t)tid * 8] = o;
}

__global__ void prep_kernel(const float* __restrict__ x, uint4* __restrict__ xbf4, int total8,
                            const float* __restrict__ W0l, const float* __restrict__ W0r,
                            ushort* __restrict__ wcat0,
                            const float* __restrict__ W1l, const float* __restrict__ W1r,
                            ushort* __restrict__ wcat1,
                            const float* __restrict__ W2l, const float* __restrict__ W2r,
                            ushort* __restrict__ wcat3, int B0) {
    int bid = blockIdx.x;
    if (bid < B0) {
        int i = bid * 256 + threadIdx.x;
        if (i >= total8) return;
        const float4* in4 = (const float4*)x;
        float4 a = in4[i * 2], b = in4[i * 2 + 1];
        uint4 o;
        o.x = pack2bf(a.x, a.y);
        o.y = pack2bf(a.z, a.w);
        o.z = pack2bf(b.x, b.y);
        o.w = pack2bf(b.z, b.w);
        xbf4[i] = o;
        return;
    }
    bid -= B0;
    if (bid < 16)      wcat2F_body(bid * 256 + threadIdx.x, W0l, W0r, wcat0);   // 4096 threads
    else if (bid < 32) wcat2F_body((bid - 16) * 256 + threadIdx.x, W1l, W1r, wcat1);
    else               wcat3F_body((bid - 32) * 256 + threadIdx.x, W2l, W2r, wcat3); // 2048
}

// ---------------- dual GEMM (layers 1-2), column-split 1-wave blocks --------
// bid = (row32 << 2) | q; q selects 4 ct-tiles (64 cols). q 0-1 -> u (fp8),
// q 2-3 -> v (bf16 + bias). W fragments (16) fully register-resident.
__global__ __launch_bounds__(64, 3)
void gemm_dual_kernel(const ushort* __restrict__ Ah, const ushort* __restrict__ Wf,
                      const float* __restrict__ bias, uchar* __restrict__ u8,
                      ushort* __restrict__ v, int n) {
    int lane = threadIdx.x;
    int q = blockIdx.x & 3;
    int rowbase = (blockIdx.x >> 2) * 32;
    int lr = lane & 15, kg = lane >> 4;
    int r0 = rowbase + lr;      if (r0 > n - 1) r0 = n - 1;
    int r1 = rowbase + 16 + lr; if (r1 > n - 1) r1 = n - 1;

    // hoist A (8 loads) and W (16 loads) -- all independent, issue up front
    short8 a0[4], a1[4];
#pragma unroll
    for (int ks = 0; ks < 4; ++ks) {
        int koff = ks * 32 + kg * 8;
        a0[ks] = *(const short8*)&Ah[(size_t)r0 * 128 + koff];
        a1[ks] = *(const short8*)&Ah[(size_t)r1 * 128 + koff];
    }
    short8 w[4][4];
#pragma unroll
    for (int c = 0; c < 4; ++c)
#pragma unroll
        for (int ks = 0; ks < 4; ++ks)
            w[c][ks] = *(const short8*)&Wf[(size_t)(((q * 4 + c) * 4 + ks) * 64 + lane) * 8];

    f32x4 acc[2][4];
#pragma unroll
    for (int mr = 0; mr < 2; ++mr)
#pragma unroll
        for (int c = 0; c < 4; ++c)
#pragma unroll
            for (int j = 0; j < 4; ++j) acc[mr][c][j] = 0.f;

#pragma unroll
    for (int ks = 0; ks < 4; ++ks)
#pragma unroll
        for (int c = 0; c < 4; ++c) {
            acc[0][c] = __builtin_amdgcn_mfma_f32_16x16x32_bf16(w[c][ks], a0[ks], acc[0][c], 0, 0, 0);
            acc[1][c] = __builtin_amdgcn_mfma_f32_16x16x32_bf16(w[c][ks], a1[ks], acc[1][c], 0, 0, 0);
        }

    if (q < 2) {            // u: fp8, no bias, no relu
#pragma unroll
        for (int mr = 0; mr < 2; ++mr) {
            int r = rowbase + mr * 16 + lr;
            if (r < n) {
#pragma unroll
                for (int c = 0; c < 4; ++c) {
                    int col = (q * 4 + c) * 16 + kg * 4;
                    uint uu = pack4fp8(acc[mr][c][0], acc[mr][c][1],
                                       acc[mr][c][2], acc[mr][c][3]);
                    *(uint*)&u8[(size_t)r * 128 + col] = uu;
                }
            }
        }
    } else {                // v: bf16, +bias
#pragma unroll
        for (int mr = 0; mr < 2; ++mr) {
            int r = rowbase + mr * 16 + lr;
            if (r < n) {
#pragma unroll
                for (int c = 0; c < 4; ++c) {
                    int col = ((q - 2) * 4 + c) * 16 + kg * 4;
                    float4 b4 = *(const float4*)&bias[col];
                    uint2 o;
                    o.x = pack2bf(acc[mr][c][0] + b4.x, acc[mr][c][1] + b4.y);
                    o.y = pack2bf(acc[mr][c][2] + b4.z, acc[mr][c][3] + b4.w);
                    *(uint2*)&v[(size_t)r * 128 + col] = o;
                }
            }
        }
    }
}

// ---------------- fused layer tail: h' = ReLU(mean(u) + v) ----------------
// One 8-lane group per node (32 nodes/block); 8-deep unrolled fp8 gathers.
__global__ void agg_epi_kernel(const uint4* __restrict__ u8, const int* __restrict__ offs,
                               const int* __restrict__ deg, const int* __restrict__ csr,
                               const uint4* __restrict__ v4, uint4* __restrict__ hout, int n) {
    int node = blockIdx.x * 32 + (threadIdx.x >> 3);
    if (node >= n) return;
    int lr = threadIdx.x & 7;
    int s = offs[node], d = deg[node];
    int e = s + d;
    float acc[16];
#pragma unroll
    for (int j = 0; j < 16; ++j) acc[j] = 0.f;

    int i = s;
    for (; i + 7 < e; i += 8) {
        int idx[8];
#pragma unroll
        for (int j = 0; j < 8; ++j) idx[j] = csr[i + j];
        uint4 w[8];
#pragma unroll
        for (int j = 0; j < 8; ++j) w[j] = u8[(size_t)idx[j] * 8 + lr];
#pragma unroll
        for (int j = 0; j < 8; ++j) accf8(acc, w[j]);
    }
    if (i + 3 < e) {
        int i0 = csr[i], i1 = csr[i + 1], i2 = csr[i + 2], i3 = csr[i + 3];
        uint4 w0 = u8[(size_t)i0 * 8 + lr];
        uint4 w1 = u8[(size_t)i1 * 8 + lr];
        uint4 w2 = u8[(size_t)i2 * 8 + lr];
        uint4 w3 = u8[(size_t)i3 * 8 + lr];
        accf8(acc, w0); accf8(acc, w1); accf8(acc, w2); accf8(acc, w3);
        i += 4;
    }
    for (; i < e; ++i) accf8(acc, u8[(size_t)csr[i] * 8 + lr]);

    float inv = (d > 0) ? 1.0f / (float)d : 0.f;
    uint4 va = v4[(size_t)node * 16 + lr * 2];
    uint4 vb = v4[(size_t)node * 16 + lr * 2 + 1];
    float h[16];
    h[0]  = fmaxf(acc[0]  * inv + bflo(va.x), 0.f);
    h[1]  = fmaxf(acc[1]  * inv + bfhi(va.x), 0.f);
    h[2]  = fmaxf(acc[2]  * inv + bflo(va.y), 0.f);
    h[3]  = fmaxf(acc[3]  * inv + bfhi(va.y), 0.f);
    h[4]  = fmaxf(acc[4]  * inv + bflo(va.z), 0.f);
    h[5]  = fmaxf(acc[5]  * inv + bfhi(va.z), 0.f);
    h[6]  = fmaxf(acc[6]  * inv + bflo(va.w), 0.f);
    h[7]  = fmaxf(acc[7]  * inv + bfhi(va.w), 0.f);
    h[8]  = fmaxf(acc[8]  * inv + bflo(vb.x), 0.f);
    h[9]  = fmaxf(acc[9]  * inv + bfhi(vb.x), 0.f);
    h[10] = fmaxf(acc[10] * inv + bflo(vb.y), 0.f);
    h[11] = fmaxf(acc[11] * inv + bfhi(vb.y), 0.f);
    h[12] = fmaxf(acc[12] * inv + bflo(vb.z), 0.f);
    h[13] = fmaxf(acc[13] * inv + bfhi(vb.z), 0.f);
    h[14] = fmaxf(acc[14] * inv + bflo(vb.w), 0.f);
    h[15] = fmaxf(acc[15] * inv + bfhi(vb.w), 0.f);

    uint4 o0, o1;
    o0.x = pack2bf(h[0], h[1]);   o0.y = pack2bf(h[2], h[3]);
    o0.z = pack2bf(h[4], h[5]);   o0.w = pack2bf(h[6], h[7]);
    o1.x = pack2bf(h[8], h[9]);   o1.y = pack2bf(h[10], h[11]);
    o1.z = pack2bf(h[12], h[13]); o1.w = pack2bf(h[14], h[15]);
    hout[(size_t)node * 16 + lr * 2]     = o0;
    hout[(size_t)node * 16 + lr * 2 + 1] = o1;
}

// ---------------- layer-3 transform GEMM, column-split 1-wave blocks --------
// bid = (row32 << 1) | q1; q1 0 -> p (no bias), 1 -> q (+b2). 16 W frags.
__global__ __launch_bounds__(64, 3)
void gemm3_kernel(const ushort* __restrict__ Ah, const ushort* __restrict__ Wf3,
                  const float* __restrict__ b2, ushort* __restrict__ p,
                  ushort* __restrict__ q, int n) {
    int lane = threadIdx.x;
    int q1 = blockIdx.x & 1;
    int rowbase = (blockIdx.x >> 1) * 32;
    int lr = lane & 15, kg = lane >> 4;
    int r0 = rowbase + lr;      if (r0 > n - 1) r0 = n - 1;
    int r1 = rowbase + 16 + lr; if (r1 > n - 1) r1 = n - 1;

    short8 a0[4], a1[4];
#pragma unroll
    for (int ks = 0; ks < 4; ++ks) {
        int koff = ks * 32 + kg * 8;
        a0[ks] = *(const short8*)&Ah[(size_t)r0 * 128 + koff];
        a1[ks] = *(const short8*)&Ah[(size_t)r1 * 128 + koff];
    }
    short8 w[4][4];
#pragma unroll
    for (int c = 0; c < 4; ++c)
#pragma unroll
        for (int ks = 0; ks < 4; ++ks)
            w[c][ks] = *(const short8*)&Wf3[(size_t)(((q1 * 4 + c) * 4 + ks) * 64 + lane) * 8];

    f32x4 acc[2][4];
#pragma unroll
    for (int mr = 0; mr < 2; ++mr)
#pragma unroll
        for (int c = 0; c < 4; ++c)
#pragma unroll
            for (int j = 0; j < 4; ++j) acc[mr][c][j] = 0.f;

#pragma unroll
    for (int ks = 0; ks < 4; ++ks)
#pragma unroll
        for (int c = 0; c < 4; ++c) {
            acc[0][c] = __builtin_amdgcn_mfma_f32_16x16x32_bf16(w[c][ks], a0[ks], acc[0][c], 0, 0, 0);
            acc[1][c] = __builtin_amdgcn_mfma_f32_16x16x32_bf16(w[c][ks], a1[ks], acc[1][c], 0, 0, 0);
        }

    ushort* dstp = q1 ? q : p;
#pragma unroll
    for (int mr = 0; mr < 2; ++mr) {
        int r = rowbase + mr * 16 + lr;
        if (r >= n) continue;
#pragma unroll
        for (int c = 0; c < 4; ++c) {
            int col = c * 16 + kg * 4;
            float b0 = 0.f, b1 = 0.f, b2v = 0.f, b3 = 0.f;
            if (q1) {
                float4 b4 = *(const float4*)&b2[col];
                b0 = b4.x; b1 = b4.y; b2v = b4.z; b3 = b4.w;
            }
            uint2 o;
            o.x = pack2bf(acc[mr][c][0] + b0, acc[mr][c][1] + b1);
            o.y = pack2bf(acc[mr][c][2] + b2v, acc[mr][c][3] + b3);
            *(uint2*)&dstp[(size_t)r * 64 + col] = o;
        }
    }
}

// ---------------- fused layer-3 tail: out = log_softmax(mean_p + q) ----------
__global__ void agg64_ls_kernel(const uint4* __restrict__ p4, const int* __restrict__ offs,
                                const int* __restrict__ deg, const int* __restrict__ csr,
                                const uint4* __restrict__ q4, float* __restrict__ out, int n) {
    int node = blockIdx.x * 32 + (threadIdx.x >> 3);
    if (node >= n) return;
    int lr = threadIdx.x & 7;
    int s = offs[node], d = deg[node];
    int e = s + d;
    float acc[8];
#pragma unroll
    for (int j = 0; j < 8; ++j) acc[j] = 0.f;

    int i = s;
    for (; i + 7 < e; i += 8) {
        int idx[8];
#pragma unroll
        for (int j = 0; j < 8; ++j) idx[j] = csr[i + j];
        uint4 v[8];
#pragma unroll
        for (int j = 0; j < 8; ++j) v[j] = p4[(size_t)idx[j] * 8 + lr];
#pragma unroll
        for (int j = 0; j < 8; ++j) acc8(acc, v[j]);
    }
    if (i + 3 < e) {
        int i0 = csr[i], i1 = csr[i + 1], i2 = csr[i + 2], i3 = csr[i + 3];
        uint4 v0 = p4[(size_t)i0 * 8 + lr];
        uint4 v1 = p4[(size_t)i1 * 8 + lr];
        uint4 v2 = p4[(size_t)i2 * 8 + lr];
        uint4 v3 = p4[(size_t)i3 * 8 + lr];
        acc8(acc, v0); acc8(acc, v1); acc8(acc, v2); acc8(acc, v3);
        i += 4;
    }
    for (; i < e; ++i) acc8(acc, p4[(size_t)csr[i] * 8 + lr]);
    float inv = (d > 0) ? 1.0f / (float)d : 0.f;

    uint4 qv = q4[(size_t)node * 8 + lr];
    float v[8];
    v[0] = acc[0] * inv + bflo(qv.x); v[1] = acc[1] * inv + bfhi(qv.x);
    v[2] = acc[2] * inv + bflo(qv.y); v[3] = acc[3] * inv + bfhi(qv.y);
    v[4] = acc[4] * inv + bflo(qv.z); v[5] = acc[5] * inv + bfhi(qv.z);
    v[6] = acc[6] * inv + bflo(qv.w); v[7] = acc[7] * inv + bfhi(qv.w);

    float m = v[0];
#pragma unroll
    for (int j = 1; j < 8; ++j) m = fmaxf(m, v[j]);
#pragma unroll
    for (int dd = 1; dd < 8; dd <<= 1) m = fmaxf(m, __shfl_xor(m, dd, 64));
    float sum = 0.f;
#pragma unroll
    for (int j = 0; j < 8; ++j) sum += __expf(v[j] - m);
#pragma unroll
    for (int dd = 1; dd < 8; dd <<= 1) sum += __shfl_xor(sum, dd, 64);
    float ls = m + logf(sum);

    float4 o0, o1;
    o0.x = v[0] - ls; o0.y = v[1] - ls; o0.z = v[2] - ls; o0.w = v[3] - ls;
    o1.x = v[4] - ls; o1.y = v[5] - ls; o1.z = v[6] - ls; o1.w = v[7] - ls;
    float4* out4 = (float4*)out;
    out4[(size_t)node * 16 + lr * 2]     = o0;
    out4[(size_t)node * 16 + lr * 2 + 1] = o1;
}

extern "C" void kernel_launch(void* const* d_in, const int* in_sizes, int n_in,
                              void* d_out, int out_size, void* d_ws, size_t ws_size,
                              hipStream_t stream) {
    const float* x   = (const float*)d_in[0];
    const int*   ei  = (const int*)d_in[1];
    const float* W0l = (const float*)d_in[2];
    const float* b0  = (const float*)d_in[3];
    const float* W0r = (const float*)d_in[4];
    const float* W1l = (const float*)d_in[5];
    const float* b1  = (const float*)d_in[6];
    const float* W1r = (const float*)d_in[7];
    const float* W2l = (const float*)d_in[8];
    const float* b2  = (const float*)d_in[9];
    const float* W2r = (const float*)d_in[10];

    int n = in_sizes[0] / N_FEAT;       // 100000
    int E = in_sizes[1] / 2;            // 1600000
    const int* srcv = ei;
    const int* dstv = ei + E;
    int NB = (n + 255) >> 8;            // coarse buckets (width 256 nodes)

    // workspace layout
    char* ws = (char*)d_ws;
    int* offs    = (int*)ws;                       // n
    int* deg     = offs + n;                       // n
    int* gcursor = deg + n;                        // NBMAX
    int* csr     = gcursor + NBMAX;                // NB*BCAP (padded)
    uint* bucketArr = (uint*)(csr + (size_t)NB * BCAP);   // NB*BCAP
    size_t intbytes = ((size_t)2 * n + NBMAX + 2 * (size_t)NB * BCAP) * sizeof(int);
    intbytes = (intbytes + 255) & ~(size_t)255;
    ushort* xbf   = (ushort*)(ws + intbytes);      // n*128 bf16
    ushort* hA    = xbf + (size_t)n * N_FEAT;      // n*128
    ushort* hB    = hA + (size_t)n * N_FEAT;       // n*128
    ushort* vbuf  = hB + (size_t)n * N_FEAT;       // n*128 (v scratch, both layers)
    ushort* wcat0 = vbuf + (size_t)n * N_FEAT;     // 16*4*64*8 = 32768
    ushort* wcat1 = wcat0 + 32768;                 // 32768
    ushort* wcat3 = wcat1 + 32768;                 // 8*4*64*8 = 16384
    ushort* p3    = wcat3 + 16384;                 // n*64
    ushort* q3    = p3 + (size_t)n * 64;           // n*64
    uchar*  u8    = (uchar*)(q3 + (size_t)n * 64); // n*128 fp8 (u scratch)

    int ebGrid = (E + SCHUNK - 1) / SCHUNK;
    int total8 = n * N_FEAT / 8;
    int B0 = (total8 + 255) / 256;

    // ---- prep (independent of CSR) ----
    prep_kernel<<<B0 + 40, 256, 0, stream>>>(x, (uint4*)xbf, total8,
                                             W0l, W0r, wcat0, W1l, W1r, wcat1,
                                             W2l, W2r, wcat3, B0);

    // ---- build CSR (single-pass padded-bucket counting sort) ----
    csr_init_kernel<<<2, 256, 0, stream>>>(gcursor);
    bucket_scatter_kernel<<<ebGrid, 256, 0, stream>>>(srcv, dstv, gcursor, bucketArr, E, NB);
    bucket_build_kernel<<<NB, 256, 0, stream>>>(bucketArr, gcursor, offs, deg, csr, n);

    int aggGrid = (n + 31) / 32;
    int row32 = (n + 31) / 32;

    // ---- layer 1: u = x@W0l^T (fp8), v = x@W0r^T + b0; hA = relu(mean(u)+v) ----
    gemm_dual_kernel<<<row32 * 4, 64, 0, stream>>>(xbf, wcat0, b0, u8, vbuf, n);
    agg_epi_kernel<<<aggGrid, 256, 0, stream>>>((const uint4*)u8, offs, deg, csr,
                                                (const uint4*)vbuf, (uint4*)hA, n);
    // ---- layer 2 ----
    gemm_dual_kernel<<<row32 * 4, 64, 0, stream>>>(hA, wcat1, b1, u8, vbuf, n);
    agg_epi_kernel<<<aggGrid, 256, 0, stream>>>((const uint4*)u8, offs, deg, csr,
                                                (const uint4*)vbuf, (uint4*)hB, n);
    // ---- layer 3: transform, then fused aggregate+add+log_softmax ----
    gemm3_kernel<<<row32 * 2, 64, 0, stream>>>(hB, wcat3, b2, p3, q3, n);
    agg64_ls_kernel<<<aggGrid, 256, 0, stream>>>((const uint4*)p3, offs, deg, csr,
                                                 (const uint4*)q3, (float*)d_out, n);
}

// Round 13
// 228.611 us; speedup vs baseline: 1.4932x; 1.4932x over previous
//
#include <hip/hip_runtime.h>
#include <hip/hip_bf16.h>

// ---------------------------------------------------------------------------
// GraphSAGE 3-layer forward, transform-before-aggregate everywhere.
//   layer: h' = ReLU( mean_agg(h @ Wl^T) + h @ Wr^T + b )   (mean is linear)
// Per layer: dual GEMM (K=128, split u-block/v-block) -> u = h@Wl^T (fp8),
// v = h@Wr^T + b (bf16); then fused gather h' = ReLU(mean(u) + v).
// agg_epi uses the 4-deep unroll (8-deep spilled to scratch: 64-VGPR cap).
// CSR: single-pass padded-bucket counting sort.
// Layer 3: p = h@W2l^T in fp8 (halves final gather), fused mean+add+ls.
// ---------------------------------------------------------------------------

#define N_FEAT 128
#define NBMAX 512          // max coarse buckets (node width 256)
#define BCAP  5120         // padded bucket capacity (mean ~4092, +16 sigma)
#define SCHUNK 8192        // edges per block in scatter pass (256 thr x 32)

typedef __attribute__((ext_vector_type(8))) short short8;   // 8 bf16 = 4 VGPRs
typedef __attribute__((ext_vector_type(4))) float f32x4;
typedef __attribute__((ext_vector_type(2))) float f32x2;

__device__ __forceinline__ ushort f2bf(float f) {
    union { float f; uint u; } v; v.f = f;
    uint u = v.u;
    return (ushort)((u + 0x7fffu + ((u >> 16) & 1u)) >> 16);   // RNE
}
__device__ __forceinline__ uint pack2bf(float x, float y) {
    return (uint)f2bf(x) | ((uint)f2bf(y) << 16);
}
__device__ __forceinline__ float bflo(uint v) {
    union { uint u; float f; } c; c.u = v << 16; return c.f;
}
__device__ __forceinline__ float bfhi(uint v) {
    union { uint u; float f; } c; c.u = v & 0xffff0000u; return c.f;
}
__device__ __forceinline__ void acc8(float* acc, uint4 v) {
    acc[0] += bflo(v.x); acc[1] += bfhi(v.x);
    acc[2] += bflo(v.y); acc[3] += bfhi(v.y);
    acc[4] += bflo(v.z); acc[5] += bfhi(v.z);
    acc[6] += bflo(v.w); acc[7] += bfhi(v.w);
}
// decode 16 fp8 (uint4) -> acc[16] (fp32 accumulate)
__device__ __forceinline__ void accf8(float* acc, uint4 v) {
    f32x2 p;
    p = __builtin_amdgcn_cvt_pk_f32_fp8((int)v.x, false); acc[0] += p.x;  acc[1] += p.y;
    p = __builtin_amdgcn_cvt_pk_f32_fp8((int)v.x, true);  acc[2] += p.x;  acc[3] += p.y;
    p = __builtin_amdgcn_cvt_pk_f32_fp8((int)v.y, false); acc[4] += p.x;  acc[5] += p.y;
    p = __builtin_amdgcn_cvt_pk_f32_fp8((int)v.y, true);  acc[6] += p.x;  acc[7] += p.y;
    p = __builtin_amdgcn_cvt_pk_f32_fp8((int)v.z, false); acc[8] += p.x;  acc[9] += p.y;
    p = __builtin_amdgcn_cvt_pk_f32_fp8((int)v.z, true);  acc[10] += p.x; acc[11] += p.y;
    p = __builtin_amdgcn_cvt_pk_f32_fp8((int)v.w, false); acc[12] += p.x; acc[13] += p.y;
    p = __builtin_amdgcn_cvt_pk_f32_fp8((int)v.w, true);  acc[14] += p.x; acc[15] += p.y;
}
// decode 8 fp8 (uint2) -> acc[8]
__device__ __forceinline__ void accf8h(float* acc, uint2 v) {
    f32x2 p;
    p = __builtin_amdgcn_cvt_pk_f32_fp8((int)v.x, false); acc[0] += p.x; acc[1] += p.y;
    p = __builtin_amdgcn_cvt_pk_f32_fp8((int)v.x, true);  acc[2] += p.x; acc[3] += p.y;
    p = __builtin_amdgcn_cvt_pk_f32_fp8((int)v.y, false); acc[4] += p.x; acc[5] += p.y;
    p = __builtin_amdgcn_cvt_pk_f32_fp8((int)v.y, true);  acc[6] += p.x; acc[7] += p.y;
}
__device__ __forceinline__ uint pack4fp8(float a, float b, float c, float d) {
    int u = __builtin_amdgcn_cvt_pk_fp8_f32(a, b, 0, false);
    u = __builtin_amdgcn_cvt_pk_fp8_f32(c, d, u, true);
    return (uint)u;
}

// ---------------- block inclusive scan helper (256 threads) ----------------
__device__ __forceinline__ int block_inclusive_scan256(int v, int* lds_waves, int tid) {
    int lane = tid & 63;
    int wid  = tid >> 6;
#pragma unroll
    for (int d = 1; d < 64; d <<= 1) {
        int t = __shfl_up(v, d, 64);
        if (lane >= d) v += t;
    }
    if (lane == 63) lds_waves[wid] = v;
    __syncthreads();
    if (wid == 0) {
        int s = (lane < 4) ? lds_waves[lane] : 0;
#pragma unroll
        for (int d = 1; d < 4; d <<= 1) {
            int t = __shfl_up(s, d, 64);
            if (lane >= d) s += t;
        }
        if (lane < 4) lds_waves[lane] = s;
    }
    __syncthreads();
    int add = (wid > 0) ? lds_waves[wid - 1] : 0;
    return v + add;
}

// ---------------- init per-bucket cursors ----------------
__global__ void csr_init_kernel(int* __restrict__ gcursor) {
    int b = blockIdx.x * 256 + threadIdx.x;
    if (b < NBMAX) gcursor[b] = b * BCAP;
}

// ---------------- scatter packed (dloc<<24|src) into padded buckets ---------
__global__ void bucket_scatter_kernel(const int* __restrict__ src, const int* __restrict__ dst,
                                      int* __restrict__ gcursor, uint* __restrict__ bucketArr,
                                      int E, int NB) {
    __shared__ int cnt[NBMAX];
    __shared__ int gbase[NBMAX];
    int tid = threadIdx.x;
    for (int i = tid; i < NB; i += 256) cnt[i] = 0;
    __syncthreads();
    int base = blockIdx.x * SCHUNK;
    int4 sv[8], dv[8];
    int r[32];
#pragma unroll
    for (int b = 0; b < 8; ++b) {
        int idx = base + b * 1024 + tid * 4;
        if (idx < E) {
            sv[b] = *(const int4*)&src[idx];
            dv[b] = *(const int4*)&dst[idx];
        }
    }
#pragma unroll
    for (int b = 0; b < 8; ++b) {
        int idx = base + b * 1024 + tid * 4;
        if (idx < E) {
            r[b * 4 + 0] = atomicAdd(&cnt[dv[b].x >> 8], 1);
            r[b * 4 + 1] = atomicAdd(&cnt[dv[b].y >> 8], 1);
            r[b * 4 + 2] = atomicAdd(&cnt[dv[b].z >> 8], 1);
            r[b * 4 + 3] = atomicAdd(&cnt[dv[b].w >> 8], 1);
        }
    }
    __syncthreads();
    for (int i = tid; i < NB; i += 256)
        if (cnt[i]) gbase[i] = atomicAdd(&gcursor[i], cnt[i]);
    __syncthreads();
#pragma unroll
    for (int b = 0; b < 8; ++b) {
        int idx = base + b * 1024 + tid * 4;
        if (idx < E) {
            int ss[4] = { sv[b].x, sv[b].y, sv[b].z, sv[b].w };
            int dd[4] = { dv[b].x, dv[b].y, dv[b].z, dv[b].w };
#pragma unroll
            for (int j = 0; j < 4; ++j) {
                int bk = dd[j] >> 8;
                int pos = gbase[bk] + r[b * 4 + j];
                if (pos < (bk + 1) * BCAP) {     // overflow drop-guard
                    bucketArr[pos] = ((uint)(dd[j] & 255) << 24) | (uint)ss[j];
                }
            }
        }
    }
}

// ---------------- per-bucket CSR build: offs/deg + csr (padded) -------------
__global__ void bucket_build_kernel(const uint* __restrict__ bucketArr,
                                    const int* __restrict__ gcursor,
                                    int* __restrict__ offs, int* __restrict__ deg,
                                    int* __restrict__ csr, int n) {
    __shared__ int cnt[256];
    __shared__ int lds[4];
    int b = blockIdx.x, tid = threadIdx.x;
    int ebase = b * BCAP;
    int eend = gcursor[b];
    if (eend > ebase + BCAP) eend = ebase + BCAP;
    cnt[tid] = 0;
    __syncthreads();
    for (int i = ebase + tid; i < eend; i += 256)
        atomicAdd(&cnt[bucketArr[i] >> 24], 1);
    __syncthreads();
    int v = cnt[tid];
    int incl = block_inclusive_scan256(v, lds, tid);
    int excl = incl - v;
    int node = b * 256 + tid;
    if (node < n) { offs[node] = ebase + excl; deg[node] = v; }
    __syncthreads();
    cnt[tid] = excl;
    __syncthreads();
    for (int i = ebase + tid; i < eend; i += 256) {
        uint p = bucketArr[i];
        int pos = ebase + atomicAdd(&cnt[p >> 24], 1);
        csr[pos] = (int)(p & 0xFFFFFFu);
    }
}

// ---------------- merged prep: x->bf16 + fragment-major weight repacks ------
// Stacked [Wl;Wr] (256 rows, K=128): Wf[(ct*4+ks)*64+lane]*8, ct 0..15.
__device__ __forceinline__ void wcat2F_body(int tid, const float* Wl, const float* Wr,
                                            ushort* out) {
    int lane = tid & 63, ks = (tid >> 6) & 3, ct = tid >> 8;   // ct 0..15
    int lr = lane & 15, kg = lane >> 4;
    int row = ct * 16 + lr, k = ks * 32 + kg * 8;
    const float* s = (row < 128) ? &Wl[(size_t)row * 128 + k]
                                 : &Wr[(size_t)(row - 128) * 128 + k];
    float4 v0 = *(const float4*)s;
    float4 v1 = *(const float4*)(s + 4);
    uint4 o;
    o.x = pack2bf(v0.x, v0.y); o.y = pack2bf(v0.z, v0.w);
    o.z = pack2bf(v1.x, v1.y); o.w = pack2bf(v1.z, v1.w);
    *(uint4*)&out[(size_t)tid * 8] = o;
}
// Stacked [W2l;W2r] (128 rows): Wf3[(ct*4+ks)*64+lane]*8, ct 0..7.
__device__ __forceinline__ void wcat3F_body(int tid, const float* W2l, const float* W2r,
                                            ushort* out) {
    int lane = tid & 63, ks = (tid >> 6) & 3, ct = tid >> 8;
    int lr = lane & 15, kg = lane >> 4;
    int row = ct * 16 + lr, k = ks * 32 + kg * 8;
    const float* s = (row < 64) ? &W2l[(size_t)row * 128 + k] : &W2r[(size_t)(row - 64) * 128 + k];
    float4 v0 = *(const float4*)s;
    float4 v1 = *(const float4*)(s + 4);
    uint4 o;
    o.x = pack2bf(v0.x, v0.y); o.y = pack2bf(v0.z, v0.w);
    o.z = pack2bf(v1.x, v1.y); o.w = pack2bf(v1.z, v1.w);
    *(uint4*)&out[(size_t)tid * 8] = o;
}

__global__ void prep_kernel(const float* __restrict__ x, uint4* __restrict__ xbf4, int total8,
                            const float* __restrict__ W0l, const float* __restrict__ W0r,
                            ushort* __restrict__ wcat0,
                            const float* __restrict__ W1l, const float* __restrict__ W1r,
                            ushort* __restrict__ wcat1,
                            const float* __restrict__ W2l, const float* __restrict__ W2r,
                            ushort* __restrict__ wcat3, int B0) {
    int bid = blockIdx.x;
    if (bid < B0) {
        int i = bid * 256 + threadIdx.x;
        if (i >= total8) return;
        const float4* in4 = (const float4*)x;
        float4 a = in4[i * 2], b = in4[i * 2 + 1];
        uint4 o;
        o.x = pack2bf(a.x, a.y);
        o.y = pack2bf(a.z, a.w);
        o.z = pack2bf(b.x, b.y);
        o.w = pack2bf(b.z, b.w);
        xbf4[i] = o;
        return;
    }
    bid -= B0;
    if (bid < 16)      wcat2F_body(bid * 256 + threadIdx.x, W0l, W0r, wcat0);
    else if (bid < 32) wcat2F_body((bid - 16) * 256 + threadIdx.x, W1l, W1r, wcat1);
    else               wcat3F_body((bid - 32) * 256 + threadIdx.x, W2l, W2r, wcat3);
}

// ---------------- dual GEMM (layers 1-2), 2-way split 1-wave blocks ---------
// bid = (row32 << 1) | q; q=0 -> u = h@Wl^T (8 cts, fp8); q=1 -> v (+bias).
__global__ __launch_bounds__(64, 3)
void gemm_dual_kernel(const ushort* __restrict__ Ah, const ushort* __restrict__ Wf,
                      const float* __restrict__ bias, uchar* __restrict__ u8,
                      ushort* __restrict__ v, int n) {
    int lane = threadIdx.x;
    int q = blockIdx.x & 1;
    int rowbase = (blockIdx.x >> 1) * 32;
    int lr = lane & 15, kg = lane >> 4;
    int r0 = rowbase + lr;      if (r0 > n - 1) r0 = n - 1;
    int r1 = rowbase + 16 + lr; if (r1 > n - 1) r1 = n - 1;

    short8 a0[4], a1[4];
#pragma unroll
    for (int ks = 0; ks < 4; ++ks) {
        int koff = ks * 32 + kg * 8;
        a0[ks] = *(const short8*)&Ah[(size_t)r0 * 128 + koff];
        a1[ks] = *(const short8*)&Ah[(size_t)r1 * 128 + koff];
    }

    f32x4 acc[2][8];
#pragma unroll
    for (int mr = 0; mr < 2; ++mr)
#pragma unroll
        for (int c = 0; c < 8; ++c)
#pragma unroll
            for (int j = 0; j < 4; ++j) acc[mr][c][j] = 0.f;

#pragma unroll
    for (int ks = 0; ks < 4; ++ks) {
        short8 w[8];
#pragma unroll
        for (int c = 0; c < 8; ++c)
            w[c] = *(const short8*)&Wf[(size_t)(((q * 8 + c) * 4 + ks) * 64 + lane) * 8];
#pragma unroll
        for (int c = 0; c < 8; ++c) {
            acc[0][c] = __builtin_amdgcn_mfma_f32_16x16x32_bf16(w[c], a0[ks], acc[0][c], 0, 0, 0);
            acc[1][c] = __builtin_amdgcn_mfma_f32_16x16x32_bf16(w[c], a1[ks], acc[1][c], 0, 0, 0);
        }
    }

    if (q == 0) {           // u: fp8, no bias, no relu
#pragma unroll
        for (int mr = 0; mr < 2; ++mr) {
            int r = rowbase + mr * 16 + lr;
            if (r < n) {
#pragma unroll
                for (int c = 0; c < 8; ++c) {
                    int col = c * 16 + kg * 4;
                    uint uu = pack4fp8(acc[mr][c][0], acc[mr][c][1],
                                       acc[mr][c][2], acc[mr][c][3]);
                    *(uint*)&u8[(size_t)r * 128 + col] = uu;
                }
            }
        }
    } else {                // v: bf16, +bias
#pragma unroll
        for (int mr = 0; mr < 2; ++mr) {
            int r = rowbase + mr * 16 + lr;
            if (r < n) {
#pragma unroll
                for (int c = 0; c < 8; ++c) {
                    int col = c * 16 + kg * 4;
                    float4 b4 = *(const float4*)&bias[col];
                    uint2 o;
                    o.x = pack2bf(acc[mr][c][0] + b4.x, acc[mr][c][1] + b4.y);
                    o.y = pack2bf(acc[mr][c][2] + b4.z, acc[mr][c][3] + b4.w);
                    *(uint2*)&v[(size_t)r * 128 + col] = o;
                }
            }
        }
    }
}

// ---------------- fused layer tail: h' = ReLU(mean(u) + v) ----------------
// One 8-lane group per node (32 nodes/block); 4-deep unrolled fp8 gathers
// (8-deep spills past the 64-VGPR allocation -- measured 6x write amp).
__global__ void agg_epi_kernel(const uint4* __restrict__ u8, const int* __restrict__ offs,
                               const int* __restrict__ deg, const int* __restrict__ csr,
                               const uint4* __restrict__ v4, uint4* __restrict__ hout, int n) {
    int node = blockIdx.x * 32 + (threadIdx.x >> 3);
    if (node >= n) return;
    int lr = threadIdx.x & 7;
    int s = offs[node], d = deg[node];
    int e = s + d;
    float acc[16];
#pragma unroll
    for (int j = 0; j < 16; ++j) acc[j] = 0.f;

    int i = s;
    for (; i + 3 < e; i += 4) {
        int i0 = csr[i], i1 = csr[i + 1], i2 = csr[i + 2], i3 = csr[i + 3];
        uint4 w0 = u8[(size_t)i0 * 8 + lr];
        uint4 w1 = u8[(size_t)i1 * 8 + lr];
        uint4 w2 = u8[(size_t)i2 * 8 + lr];
        uint4 w3 = u8[(size_t)i3 * 8 + lr];
        accf8(acc, w0); accf8(acc, w1); accf8(acc, w2); accf8(acc, w3);
    }
    for (; i < e; ++i) accf8(acc, u8[(size_t)csr[i] * 8 + lr]);

    float inv = (d > 0) ? 1.0f / (float)d : 0.f;
    uint4 va = v4[(size_t)node * 16 + lr * 2];
    uint4 vb = v4[(size_t)node * 16 + lr * 2 + 1];
    float h[16];
    h[0]  = fmaxf(acc[0]  * inv + bflo(va.x), 0.f);
    h[1]  = fmaxf(acc[1]  * inv + bfhi(va.x), 0.f);
    h[2]  = fmaxf(acc[2]  * inv + bflo(va.y), 0.f);
    h[3]  = fmaxf(acc[3]  * inv + bfhi(va.y), 0.f);
    h[4]  = fmaxf(acc[4]  * inv + bflo(va.z), 0.f);
    h[5]  = fmaxf(acc[5]  * inv + bfhi(va.z), 0.f);
    h[6]  = fmaxf(acc[6]  * inv + bflo(va.w), 0.f);
    h[7]  = fmaxf(acc[7]  * inv + bfhi(va.w), 0.f);
    h[8]  = fmaxf(acc[8]  * inv + bflo(vb.x), 0.f);
    h[9]  = fmaxf(acc[9]  * inv + bfhi(vb.x), 0.f);
    h[10] = fmaxf(acc[10] * inv + bflo(vb.y), 0.f);
    h[11] = fmaxf(acc[11] * inv + bfhi(vb.y), 0.f);
    h[12] = fmaxf(acc[12] * inv + bflo(vb.z), 0.f);
    h[13] = fmaxf(acc[13] * inv + bfhi(vb.z), 0.f);
    h[14] = fmaxf(acc[14] * inv + bflo(vb.w), 0.f);
    h[15] = fmaxf(acc[15] * inv + bfhi(vb.w), 0.f);

    uint4 o0, o1;
    o0.x = pack2bf(h[0], h[1]);   o0.y = pack2bf(h[2], h[3]);
    o0.z = pack2bf(h[4], h[5]);   o0.w = pack2bf(h[6], h[7]);
    o1.x = pack2bf(h[8], h[9]);   o1.y = pack2bf(h[10], h[11]);
    o1.z = pack2bf(h[12], h[13]); o1.w = pack2bf(h[14], h[15]);
    hout[(size_t)node * 16 + lr * 2]     = o0;
    hout[(size_t)node * 16 + lr * 2 + 1] = o1;
}

// ---------------- layer-3 transform GEMM, 2-way split 1-wave blocks ---------
// bid = (row32 << 1) | q1; q1=0 -> p (fp8, no bias), q1=1 -> q (bf16, +b2).
__global__ __launch_bounds__(64, 3)
void gemm3_kernel(const ushort* __restrict__ Ah, const ushort* __restrict__ Wf3,
                  const float* __restrict__ b2, uchar* __restrict__ p8,
                  ushort* __restrict__ q, int n) {
    int lane = threadIdx.x;
    int q1 = blockIdx.x & 1;
    int rowbase = (blockIdx.x >> 1) * 32;
    int lr = lane & 15, kg = lane >> 4;
    int r0 = rowbase + lr;      if (r0 > n - 1) r0 = n - 1;
    int r1 = rowbase + 16 + lr; if (r1 > n - 1) r1 = n - 1;

    short8 a0[4], a1[4];
#pragma unroll
    for (int ks = 0; ks < 4; ++ks) {
        int koff = ks * 32 + kg * 8;
        a0[ks] = *(const short8*)&Ah[(size_t)r0 * 128 + koff];
        a1[ks] = *(const short8*)&Ah[(size_t)r1 * 128 + koff];
    }

    f32x4 acc[2][4];
#pragma unroll
    for (int mr = 0; mr < 2; ++mr)
#pragma unroll
        for (int c = 0; c < 4; ++c)
#pragma unroll
            for (int j = 0; j < 4; ++j) acc[mr][c][j] = 0.f;

#pragma unroll
    for (int ks = 0; ks < 4; ++ks) {
        short8 w[4];
#pragma unroll
        for (int c = 0; c < 4; ++c)
            w[c] = *(const short8*)&Wf3[(size_t)(((q1 * 4 + c) * 4 + ks) * 64 + lane) * 8];
#pragma unroll
        for (int c = 0; c < 4; ++c) {
            acc[0][c] = __builtin_amdgcn_mfma_f32_16x16x32_bf16(w[c], a0[ks], acc[0][c], 0, 0, 0);
            acc[1][c] = __builtin_amdgcn_mfma_f32_16x16x32_bf16(w[c], a1[ks], acc[1][c], 0, 0, 0);
        }
    }

    if (q1 == 0) {          // p: fp8
#pragma unroll
        for (int mr = 0; mr < 2; ++mr) {
            int r = rowbase + mr * 16 + lr;
            if (r < n) {
#pragma unroll
                for (int c = 0; c < 4; ++c) {
                    int col = c * 16 + kg * 4;
                    uint uu = pack4fp8(acc[mr][c][0], acc[mr][c][1],
                                       acc[mr][c][2], acc[mr][c][3]);
                    *(uint*)&p8[(size_t)r * 64 + col] = uu;
                }
            }
        }
    } else {                // q: bf16 + b2
#pragma unroll
        for (int mr = 0; mr < 2; ++mr) {
            int r = rowbase + mr * 16 + lr;
            if (r < n) {
#pragma unroll
                for (int c = 0; c < 4; ++c) {
                    int col = c * 16 + kg * 4;
                    float4 b4 = *(const float4*)&b2[col];
                    uint2 o;
                    o.x = pack2bf(acc[mr][c][0] + b4.x, acc[mr][c][1] + b4.y);
                    o.y = pack2bf(acc[mr][c][2] + b4.z, acc[mr][c][3] + b4.w);
                    *(uint2*)&q[(size_t)r * 64 + col] = o;
                }
            }
        }
    }
}

// ---------------- fused layer-3 tail: out = log_softmax(mean_p + q) ----------
// One 8-lane group per node; p rows are 64 B fp8 -> uint2 per lane.
__global__ void agg64_ls_kernel(const uint2* __restrict__ p8, const int* __restrict__ offs,
                                const int* __restrict__ deg, const int* __restrict__ csr,
                                const uint4* __restrict__ q4, float* __restrict__ out, int n) {
    int node = blockIdx.x * 32 + (threadIdx.x >> 3);
    if (node >= n) return;
    int lr = threadIdx.x & 7;
    int s = offs[node], d = deg[node];
    int e = s + d;
    float acc[8];
#pragma unroll
    for (int j = 0; j < 8; ++j) acc[j] = 0.f;

    int i = s;
    for (; i + 3 < e; i += 4) {
        int i0 = csr[i], i1 = csr[i + 1], i2 = csr[i + 2], i3 = csr[i + 3];
        uint2 w0 = p8[(size_t)i0 * 8 + lr];
        uint2 w1 = p8[(size_t)i1 * 8 + lr];
        uint2 w2 = p8[(size_t)i2 * 8 + lr];
        uint2 w3 = p8[(size_t)i3 * 8 + lr];
        accf8h(acc, w0); accf8h(acc, w1); accf8h(acc, w2); accf8h(acc, w3);
    }
    for (; i < e; ++i) accf8h(acc, p8[(size_t)csr[i] * 8 + lr]);
    float inv = (d > 0) ? 1.0f / (float)d : 0.f;

    uint4 qv = q4[(size_t)node * 8 + lr];
    float v[8];
    v[0] = acc[0] * inv + bflo(qv.x); v[1] = acc[1] * inv + bfhi(qv.x);
    v[2] = acc[2] * inv + bflo(qv.y); v[3] = acc[3] * inv + bfhi(qv.y);
    v[4] = acc[4] * inv + bflo(qv.z); v[5] = acc[5] * inv + bfhi(qv.z);
    v[6] = acc[6] * inv + bflo(qv.w); v[7] = acc[7] * inv + bfhi(qv.w);

    float m = v[0];
#pragma unroll
    for (int j = 1; j < 8; ++j) m = fmaxf(m, v[j]);
#pragma unroll
    for (int dd = 1; dd < 8; dd <<= 1) m = fmaxf(m, __shfl_xor(m, dd, 64));
    float sum = 0.f;
#pragma unroll
    for (int j = 0; j < 8; ++j) sum += __expf(v[j] - m);
#pragma unroll
    for (int dd = 1; dd < 8; dd <<= 1) sum += __shfl_xor(sum, dd, 64);
    float ls = m + logf(sum);

    float4 o0, o1;
    o0.x = v[0] - ls; o0.y = v[1] - ls; o0.z = v[2] - ls; o0.w = v[3] - ls;
    o1.x = v[4] - ls; o1.y = v[5] - ls; o1.z = v[6] - ls; o1.w = v[7] - ls;
    float4* out4 = (float4*)out;
    out4[(size_t)node * 16 + lr * 2]     = o0;
    out4[(size_t)node * 16 + lr * 2 + 1] = o1;
}

extern "C" void kernel_launch(void* const* d_in, const int* in_sizes, int n_in,
                              void* d_out, int out_size, void* d_ws, size_t ws_size,
                              hipStream_t stream) {
    const float* x   = (const float*)d_in[0];
    const int*   ei  = (const int*)d_in[1];
    const float* W0l = (const float*)d_in[2];
    const float* b0  = (const float*)d_in[3];
    const float* W0r = (const float*)d_in[4];
    const float* W1l = (const float*)d_in[5];
    const float* b1  = (const float*)d_in[6];
    const float* W1r = (const float*)d_in[7];
    const float* W2l = (const float*)d_in[8];
    const float* b2  = (const float*)d_in[9];
    const float* W2r = (const float*)d_in[10];

    int n = in_sizes[0] / N_FEAT;       // 100000
    int E = in_sizes[1] / 2;            // 1600000
    const int* srcv = ei;
    const int* dstv = ei + E;
    int NB = (n + 255) >> 8;            // coarse buckets (width 256 nodes)

    // workspace layout
    char* ws = (char*)d_ws;
    int* offs    = (int*)ws;                       // n
    int* deg     = offs + n;                       // n
    int* gcursor = deg + n;                        // NBMAX
    int* csr     = gcursor + NBMAX;                // NB*BCAP (padded)
    uint* bucketArr = (uint*)(csr + (size_t)NB * BCAP);   // NB*BCAP
    size_t intbytes = ((size_t)2 * n + NBMAX + 2 * (size_t)NB * BCAP) * sizeof(int);
    intbytes = (intbytes + 255) & ~(size_t)255;
    ushort* xbf   = (ushort*)(ws + intbytes);      // n*128 bf16
    ushort* hA    = xbf + (size_t)n * N_FEAT;      // n*128
    ushort* hB    = hA + (size_t)n * N_FEAT;       // n*128
    ushort* vbuf  = hB + (size_t)n * N_FEAT;       // n*128 (v scratch, both layers)
    ushort* wcat0 = vbuf + (size_t)n * N_FEAT;     // 16*4*64*8 = 32768
    ushort* wcat1 = wcat0 + 32768;                 // 32768
    ushort* wcat3 = wcat1 + 32768;                 // 8*4*64*8 = 16384
    ushort* q3    = wcat3 + 16384;                 // n*64 bf16
    uchar*  u8    = (uchar*)(q3 + (size_t)n * 64); // n*128 fp8 (u scratch)
    uchar*  p8    = u8 + (size_t)n * N_FEAT;       // n*64 fp8 (layer-3 p)

    int ebGrid = (E + SCHUNK - 1) / SCHUNK;
    int total8 = n * N_FEAT / 8;
    int B0 = (total8 + 255) / 256;

    // ---- prep (independent of CSR) ----
    prep_kernel<<<B0 + 40, 256, 0, stream>>>(x, (uint4*)xbf, total8,
                                             W0l, W0r, wcat0, W1l, W1r, wcat1,
                                             W2l, W2r, wcat3, B0);

    // ---- build CSR (single-pass padded-bucket counting sort) ----
    csr_init_kernel<<<2, 256, 0, stream>>>(gcursor);
    bucket_scatter_kernel<<<ebGrid, 256, 0, stream>>>(srcv, dstv, gcursor, bucketArr, E, NB);
    bucket_build_kernel<<<NB, 256, 0, stream>>>(bucketArr, gcursor, offs, deg, csr, n);

    int aggGrid = (n + 31) / 32;
    int row32 = (n + 31) / 32;

    // ---- layer 1: u = x@W0l^T (fp8), v = x@W0r^T + b0; hA = relu(mean(u)+v) ----
    gemm_dual_kernel<<<row32 * 2, 64, 0, stream>>>(xbf, wcat0, b0, u8, vbuf, n);
    agg_epi_kernel<<<aggGrid, 256, 0, stream>>>((const uint4*)u8, offs, deg, csr,
                                                (const uint4*)vbuf, (uint4*)hA, n);
    // ---- layer 2 ----
    gemm_dual_kernel<<<row32 * 2, 64, 0, stream>>>(hA, wcat1, b1, u8, vbuf, n);
    agg_epi_kernel<<<aggGrid, 256, 0, stream>>>((const uint4*)u8, offs, deg, csr,
                                                (const uint4*)vbuf, (uint4*)hB, n);
    // ---- layer 3: transform (p fp8), then fused aggregate+add+log_softmax ----
    gemm3_kernel<<<row32 * 2, 64, 0, stream>>>(hB, wcat3, b2, p8, q3, n);
    agg64_ls_kernel<<<aggGrid, 256, 0, stream>>>((const uint2*)p8, offs, deg, csr,
                                                 (const uint4*)q3, (float*)d_out, n);
}